// Round 5
// baseline (312.907 us; speedup 1.0000x reference)
//
#include <hip/hip_runtime.h>
#include <hip/hip_fp16.h>
#include <math.h>

#define S_LEN 8192
#define D_DIM 1024
#define B_DIM 4
#define M_DIM (B_DIM * S_LEN)          // 32768
#define BSD   ((size_t)M_DIM * D_DIM)
#define CHN   (B_DIM * D_DIM)          // 4096 channels
#define CHUNK 64
#define NCH   (S_LEN / CHUNK)          // 128

typedef _Float16 f16x8 __attribute__((ext_vector_type(8)));
typedef __attribute__((ext_vector_type(4))) float f32x4;
typedef unsigned int u32;

__device__ __forceinline__ u32 pk2h(float a, float b) {
    auto h = __builtin_amdgcn_cvt_pkrtz(a, b);
    u32 r; __builtin_memcpy(&r, &h, 4); return r;
}

__device__ __forceinline__ void gload16(const void* g, void* l) {
    __builtin_amdgcn_global_load_lds(
        (const __attribute__((address_space(1))) u32*)g,
        (__attribute__((address_space(3))) u32*)l,
        16, 0, 0);
}

// ---------------------------------------------------------------------------
// Kernel 0: W [1024][2048] fp32 -> Wt [2048][1024] fp16 (transposed), once.
// ---------------------------------------------------------------------------
__global__ __launch_bounds__(256) void w_to_f16t(
    const float* __restrict__ W, unsigned short* __restrict__ Wt)
{
    __shared__ float T[64][65];
    const int t  = threadIdx.x;
    const int n0 = (int)blockIdx.x * 64;
    const int k0 = (int)blockIdx.y * 64;
    #pragma unroll
    for (int p = 0; p < 4; ++p) {
        int u = p * 256 + t;
        int r = u >> 4, c4 = (u & 15) * 4;
        float4 v = *(const float4*)&W[(size_t)(k0 + r) * 2048 + n0 + c4];
        T[r][c4 + 0] = v.x; T[r][c4 + 1] = v.y;
        T[r][c4 + 2] = v.z; T[r][c4 + 3] = v.w;
    }
    __syncthreads();
    #pragma unroll
    for (int p = 0; p < 2; ++p) {
        int u = p * 256 + t;
        int n = u >> 3, kc = (u & 7) * 8;
        u32 out[4];
        #pragma unroll
        for (int j = 0; j < 4; ++j)
            out[j] = pk2h(T[kc + 2 * j][n], T[kc + 2 * j + 1][n]);
        *(uint4*)&Wt[(size_t)(n0 + n) * 1024 + k0 + kc] = *(uint4*)out;
    }
}

// ---------------------------------------------------------------------------
// Kernel 0b: x fp32 -> xh fp16, LINEAR (r21: BK=32 rows are 64B -> fragment
// reads are contiguous-1KB, inherently bank-conflict-free; swizzle deleted).
// ---------------------------------------------------------------------------
__global__ __launch_bounds__(256) void x_to_f16(
    const float* __restrict__ x, unsigned short* __restrict__ xh)
{
    int tid = (int)blockIdx.x * 256 + threadIdx.x;
    int m  = tid >> 7;
    int cg = tid & 127;
    const float4* src = (const float4*)&x[(size_t)m * 1024 + cg * 8];
    float4 v0 = src[0], v1 = src[1];
    u32 o[4] = { pk2h(v0.x, v0.y), pk2h(v0.z, v0.w),
                 pk2h(v1.x, v1.y), pk2h(v1.z, v1.w) };
    *(uint4*)&xh[(size_t)m * 1024 + cg * 8] = *(uint4*)o;
}

// ---------------------------------------------------------------------------
// Kernel 1 (main): de-correlated 2-blocks/CU MFMA GEMM (r21).
// Diagnosis chain: r18 (2.75x HBM at zero cost) exonerated memory; r17/r20
// showed sched freedom & L2-direct-B hurt; r19 (reg pipelining) gained only
// 6% -- because all 8 waves share ONE barrier domain at 1 block/CU: every
// lgkm/vmcnt/barrier drain idles the whole CU. m97's 874 TF came from ~3
// independent blocks/CU de-correlating stalls (m114 implicit overlap).
// r21 geometry: 256-thr blocks (4 waves, 2m x 2d), per-wave 128m x 64n
// (32 H-cols + 32 G-cols) keeps the 0.375 ds_read:MFMA ratio; BK=32,
// tile 256m x 64d, grid 2048. LDS 48 KB -> 2 blocks/CU (8 waves/CU, two
// independent barrier domains). BK=32 rows = 64B: a wave's fragment read
// covers 16 consecutive rows fully = contiguous 1KB = conflict-free with
// NO swizzle (xh linear; Wt rows used linearly).
// Loop = m97 skeleton: stage(t+1) | 12 ds_reads | lgkm(2) | 16 MFMA H |
// lgkm(0) | 16 MFMA G | vmcnt(0) | barrier.  Stall residue overlaps with
// the co-resident block.
// ---------------------------------------------------------------------------
__global__ __launch_bounds__(256, 2) void gemm_dc(
    const unsigned short* __restrict__ xh, const unsigned short* __restrict__ Wt,
    const int* __restrict__ ids, u32* __restrict__ P)
{
    __shared__ __align__(16) unsigned short Ah[2 * 256 * 32]; // 2 x 16 KB
    __shared__ __align__(16) unsigned short Bh[2 * 128 * 32]; // 2 x  8 KB

    const int t    = threadIdx.x;
    const int lane = t & 63;
    const int wid  = t >> 6;        // 0..3
    const int wm   = wid >> 1;      // 0..1 : 128-row half
    const int wd   = wid & 1;       // 0..1 : 32-dcol group

    const int lin  = (int)blockIdx.x;   // 2048 blocks
    const int xcd  = lin & 7;
    const int slot = lin >> 3;          // 0..255
    const int m0   = (slot & 127) * 256;
    const int c0   = (((slot >> 7) << 3) | xcd) * 64;   // 16 d-tiles, 2/XCD

    f32x4 accH[8][2], accG[8][2];
    #pragma unroll
    for (int i = 0; i < 8; ++i)
        #pragma unroll
        for (int j = 0; j < 2; ++j) {
            accH[i][j] = (f32x4)0.0f;
            accG[i][j] = (f32x4)0.0f;
        }

    // stage full A tile 256x32 (4 gload16/thread) -- linear src, linear dest
    auto stageA = [&](int kb, int buf) {
        char* Ad = (char*)Ah + buf * 16384;
        #pragma unroll
        for (int i = 0; i < 4; ++i) {
            int sl  = i * 256 + t;            // 0..1023
            int row = sl >> 2;                // 0..255
            int c   = sl & 3;
            const unsigned short* src =
                xh + ((size_t)(m0 + row) << 10) + kb + (c << 3);
            gload16(src, Ad + sl * 16);
        }
    };
    // stage full B tile 128x32 (64 H rows + 64 G rows) (2 gload16/thread)
    auto stageB = [&](int kb, int buf) {
        char* Bd = (char*)Bh + buf * 8192;
        #pragma unroll
        for (int i = 0; i < 2; ++i) {
            int sl  = i * 256 + t;            // 0..511
            int row = sl >> 2;                // 0..127
            int c   = sl & 3;
            int grow = (row >> 6) * 1024 + c0 + (row & 63);
            const unsigned short* src =
                Wt + ((size_t)grow << 10) + kb + (c << 3);
            gload16(src, Bd + sl * 16);
        }
    };

    // fragment reads: 16 consecutive 64B rows, full row -> contiguous 1KB
    auto readA = [&](const char* Ab, f16x8 a[8]) {
        #pragma unroll
        for (int mf = 0; mf < 8; ++mf) {
            int row = wm * 128 + mf * 16 + (lane & 15);
            a[mf] = *(const f16x8*)(Ab + row * 64 + ((lane >> 4) << 4));
        }
    };
    auto readB = [&](const char* Bb, int hg, f16x8 b[2]) {
        #pragma unroll
        for (int df = 0; df < 2; ++df) {
            int row = hg * 64 + wd * 32 + df * 16 + (lane & 15);
            b[df] = *(const f16x8*)(Bb + row * 64 + ((lane >> 4) << 4));
        }
    };

    #define MMA_CLUSTER(ACC, AV, BV)                                       \
        __builtin_amdgcn_s_setprio(1);                                     \
        _Pragma("unroll")                                                  \
        for (int mf = 0; mf < 8; ++mf)                                     \
            _Pragma("unroll")                                              \
            for (int df = 0; df < 2; ++df)                                 \
                ACC[mf][df] = __builtin_amdgcn_mfma_f32_16x16x32_f16(      \
                    AV[mf], BV[df], ACC[mf][df], 0, 0, 0);                 \
        __builtin_amdgcn_s_setprio(0);

    // ---- prologue: stage tile 0 ----
    stageA(0, 0); stageB(0, 0);
    asm volatile("s_waitcnt vmcnt(0)" ::: "memory");
    __builtin_amdgcn_sched_barrier(0);
    __builtin_amdgcn_s_barrier();

    for (int tt = 0; tt < 32; ++tt) {
        const int buf   = tt & 1;
        const bool more = tt < 31;
        const char* Ab = (const char*)Ah + buf * 16384;
        const char* Bb = (const char*)Bh + buf * 8192;
        f16x8 a[8], bh[2], bg[2];

        if (more) { stageA((tt + 1) * 32, buf ^ 1); stageB((tt + 1) * 32, buf ^ 1); }
        readA(Ab, a); readB(Bb, 0, bh); readB(Bb, 1, bg);
        asm volatile("s_waitcnt lgkmcnt(2)" ::: "memory");  // a+bh done
        __builtin_amdgcn_sched_barrier(0);
        MMA_CLUSTER(accH, a, bh)
        asm volatile("s_waitcnt lgkmcnt(0)" ::: "memory");  // bg done
        __builtin_amdgcn_sched_barrier(0);
        MMA_CLUSTER(accG, a, bg)
        if (more) {
            asm volatile("s_waitcnt vmcnt(0)" ::: "memory");
            __builtin_amdgcn_sched_barrier(0);
            __builtin_amdgcn_s_barrier();      // publishes buf^1, protects buf
        }
    }
    #undef MMA_CLUSTER

    // ---- linear-space epilogue: C layout col=lane&15, row=(lane>>4)*4+r ----
    #pragma unroll
    for (int mf = 0; mf < 8; ++mf) {
        int mbase = m0 + wm * 128 + mf * 16 + (lane >> 4) * 4;
        #pragma unroll
        for (int r = 0; r < 4; ++r) {
            int m = mbase + r;
            int b = m >> 13;
            int s = m & 8191;
            bool reset = (s > 0) && (ids[b * S_LEN + s - 1] == 0);
            #pragma unroll
            for (int df = 0; df < 2; ++df) {
                int d = c0 + wd * 32 + df * 16 + (lane & 15);
                float hid = accH[mf][df][r];
                float g   = accG[mf][df][r];
                float eg  = __expf(-g);
                float z   = 1.0f / (1.0f + eg);
                float c   = eg * z;
                float gt  = (hid >= 0.0f) ? (hid + 0.5f)
                                          : 1.0f / (1.0f + __expf(-hid));
                float v   = z * gt;
                if (reset) { c = 0.0f; v = 0.0f; }
                __half2 h2 = __floats2half2_rn(c, v);
                u32 packed;
                __builtin_memcpy(&packed, &h2, 4);
                P[(size_t)m * D_DIM + d] = packed;
            }
        }
    }
}

// ---------------------------------------------------------------------------
// Kernel 1 (fallback, ws too small): r10 kernel verbatim.
// ---------------------------------------------------------------------------
__global__ __launch_bounds__(256, 3) void gemm_fb(
    const float* __restrict__ x, const unsigned short* __restrict__ Wt,
    const int* __restrict__ ids, u32* __restrict__ P)
{
    __shared__ __align__(16) unsigned short Ah[128 * 64];
    __shared__ __align__(16) unsigned short Bt[2 * 64 * 64];

    const int t    = threadIdx.x;
    const int lane = t & 63;
    const int wid  = t >> 6;
    const int wm   = wid >> 1;
    const int wd   = wid & 1;

    const int lin  = (int)blockIdx.y * (int)gridDim.x + (int)blockIdx.x;
    const int xcd  = lin & 7;
    const int slot = lin >> 3;
    const int m0   = (xcd * 32 + (slot >> 4)) * 128;
    const int c0   = (slot & 15) * 64;

    f32x4 accH[4][2], accG[4][2];
    #pragma unroll
    for (int i = 0; i < 4; ++i)
        #pragma unroll
        for (int j = 0; j < 2; ++j) {
            accH[i][j] = (f32x4)0.0f;
            accG[i][j] = (f32x4)0.0f;
        }

    for (int kb = 0; kb < 1024; kb += 64) {
        __syncthreads();
        #pragma unroll
        for (int i = 0; i < 4; ++i) {
            int slotb = wid * 256 + i * 64;
            int sl  = slotb + lane;
            int hg  = sl >> 9;
            int col = (sl >> 3) & 63;
            int kc  = (sl & 7) ^ (col & 7);
            const unsigned short* src =
                Wt + ((size_t)(hg * 1024 + c0 + col) << 10) + kb + (kc << 3);
            gload16(src, (char*)Bt + (size_t)slotb * 16);
        }
        #pragma unroll
        for (int p = 0; p < 8; ++p) {
            int s   = p * 256 + t;
            int row = s >> 4;
            int c4  = s & 15;
            float4 v = *(const float4*)&x[(size_t)(m0 + row) * 1024 + kb + c4 * 4];
            uint2 h;
            h.x = pk2h(v.x, v.y);
            h.y = pk2h(v.z, v.w);
            int byte = row * 128 + ((((c4 >> 1) ^ (row & 7))) << 4) + ((c4 & 1) << 3);
            *(uint2*)((char*)Ah + byte) = h;
        }
        __syncthreads();
        #pragma unroll
        for (int kk = 0; kk < 2; ++kk) {
            f16x8 bh[2], bg[2];
            #pragma unroll
            for (int df = 0; df < 2; ++df) {
                int col = wd * 32 + df * 16 + (lane & 15);
                int chunk = kk * 4 + (lane >> 4);
                int byte = col * 128 + ((chunk ^ (col & 7)) << 4);
                bh[df] = *(const f16x8*)((const char*)Bt + byte);
                bg[df] = *(const f16x8*)((const char*)Bt + 8192 + byte);
            }
            #pragma unroll
            for (int mf = 0; mf < 4; ++mf) {
                int row = wm * 64 + mf * 16 + (lane & 15);
                int chunk = kk * 4 + (lane >> 4);
                int byte = row * 128 + ((chunk ^ (row & 7)) << 4);
                f16x8 a = *(const f16x8*)((const char*)Ah + byte);
                #pragma unroll
                for (int df = 0; df < 2; ++df) {
                    accH[mf][df] = __builtin_amdgcn_mfma_f32_16x16x32_f16(
                        a, bh[df], accH[mf][df], 0, 0, 0);
                    accG[mf][df] = __builtin_amdgcn_mfma_f32_16x16x32_f16(
                        a, bg[df], accG[mf][df], 0, 0, 0);
                }
            }
        }
    }

    #pragma unroll
    for (int mf = 0; mf < 4; ++mf) {
        int mbase = m0 + wm * 64 + mf * 16 + (lane >> 4) * 4;
        #pragma unroll
        for (int r = 0; r < 4; ++r) {
            int m = mbase + r;
            int b = m >> 13;
            int s = m & 8191;
            bool reset = (s > 0) && (ids[b * S_LEN + s - 1] == 0);
            #pragma unroll
            for (int df = 0; df < 2; ++df) {
                int d = c0 + wd * 32 + df * 16 + (lane & 15);
                float hid = accH[mf][df][r];
                float g   = accG[mf][df][r];
                float eg  = __expf(-g);
                float z   = 1.0f / (1.0f + eg);
                float c   = eg * z;
                float gt  = (hid >= 0.0f) ? (hid + 0.5f)
                                          : 1.0f / (1.0f + __expf(-hid));
                float v   = z * gt;
                if (reset) { c = 0.0f; v = 0.0f; }
                __half2 h2 = __floats2half2_rn(c, v);
                u32 packed;
                __builtin_memcpy(&packed, &h2, 4);
                P[(size_t)m * D_DIM + d] = packed;
            }
        }
    }
}

// ---------------------------------------------------------------------------
// Scan phases, linear space: h_s = c_s * h_{s-1} + v_s. Pure FMA.
// ---------------------------------------------------------------------------
__global__ __launch_bounds__(256) void scan_phase_a(
    const u32* __restrict__ P,
    float* __restrict__ Cp, float* __restrict__ Lp)
{
    int ch0 = (blockIdx.x * 256 + threadIdx.x) * 4;
    int c   = blockIdx.y;
    int b   = ch0 >> 10;
    int d0  = ch0 & 1023;
    size_t base = (size_t)b * S_LEN * D_DIM + d0;
    int s0 = c * CHUNK;

    float C[4] = {1.f, 1.f, 1.f, 1.f};
    float H[4] = {0.f, 0.f, 0.f, 0.f};
    for (int s = 0; s < CHUNK; ++s) {
        uint4 q = *(const uint4*)&P[base + (size_t)(s0 + s) * D_DIM];
        u32 qs[4] = {q.x, q.y, q.z, q.w};
        #pragma unroll
        for (int j = 0; j < 4; ++j) {
            __half2 h2;
            __builtin_memcpy(&h2, &qs[j], 4);
            float cc = __low2float(h2);
            float vv = __high2float(h2);
            H[j] = fmaf(cc, H[j], vv);
            C[j] *= cc;
        }
    }
    *(float4*)&Cp[c * CHN + ch0] = *(float4*)C;
    *(float4*)&Lp[c * CHN + ch0] = *(float4*)H;
}

__global__ __launch_bounds__(256) void scan_phase_b(
    const float* __restrict__ Cp, const float* __restrict__ Lp,
    float* __restrict__ carry)
{
    int ch = blockIdx.x * 256 + threadIdx.x;
    float h = 0.0f;
    for (int c = 0; c < NCH; ++c) {
        carry[c * CHN + ch] = h;
        h = fmaf(Cp[c * CHN + ch], h, Lp[c * CHN + ch]);
    }
}

__global__ __launch_bounds__(256) void scan_phase_c(
    u32* __restrict__ Pio,
    const float* __restrict__ carry,
    const int* __restrict__ ids)
{
    int ch0 = (blockIdx.x * 256 + threadIdx.x) * 4;
    int c   = blockIdx.y;
    int b   = ch0 >> 10;
    int d0  = ch0 & 1023;
    size_t base = (size_t)b * S_LEN * D_DIM + d0;
    int s0 = c * CHUNK;

    float H[4];
    *(float4*)H = *(const float4*)&carry[c * CHN + ch0];

    for (int s = 0; s < CHUNK; ++s) {
        size_t idx = base + (size_t)(s0 + s) * D_DIM;
        uint4 q = *(const uint4*)&Pio[idx];
        u32 qs[4] = {q.x, q.y, q.z, q.w};
        u32 os[4];
        #pragma unroll
        for (int j = 0; j < 4; ++j) {
            __half2 h2;
            __builtin_memcpy(&h2, &qs[j], 4);
            float cc = __low2float(h2);
            float vv = __high2float(h2);
            H[j] = fmaf(cc, H[j], vv);
            os[j] = __float_as_uint(H[j]);
        }
        *(uint4*)&Pio[idx] = *(uint4*)os;
    }
    if (c == NCH - 1) {
        bool pad = (ids[b * S_LEN + (S_LEN - 1)] == 0);
        u32 os[4];
        #pragma unroll
        for (int j = 0; j < 4; ++j)
            os[j] = __float_as_uint(pad ? 0.0f : H[j]);
        *(uint4*)&Pio[BSD + (size_t)b * D_DIM + d0] = *(uint4*)os;
    }
}

extern "C" void kernel_launch(void* const* d_in, const int* in_sizes, int n_in,
                              void* d_out, int out_size, void* d_ws, size_t ws_size,
                              hipStream_t stream) {
    const float* x   = (const float*)d_in[0];
    const float* W   = (const float*)d_in[1];
    const int*   ids = (const int*)d_in[2];

    u32* P = (u32*)d_out;
    unsigned short* Wt = (unsigned short*)d_ws;                   // 4 MB @ 0
    float* Cp    = (float*)((char*)d_ws + (size_t) 4 * 1024 * 1024);
    float* Lp    = (float*)((char*)d_ws + (size_t) 6 * 1024 * 1024);
    float* carry = (float*)((char*)d_ws + (size_t) 8 * 1024 * 1024);
    unsigned short* xh = (unsigned short*)((char*)d_ws + (size_t)10 * 1024 * 1024);
    const size_t need = (size_t)10 * 1024 * 1024 + BSD * 2;       // 74 MB

    w_to_f16t<<<dim3(32, 16), 256, 0, stream>>>(W, Wt);

    if (ws_size >= need) {
        x_to_f16<<<(M_DIM * 128) / 256, 256, 0, stream>>>(x, xh);
        gemm_dc<<<2048, 256, 0, stream>>>(xh, Wt, ids, P);
    } else {
        dim3 ggrid(D_DIM / 64, M_DIM / 128);
        gemm_fb<<<ggrid, 256, 0, stream>>>(x, Wt, ids, P);
    }

    dim3 sgrid(CHN / 1024, NCH);
    scan_phase_a<<<sgrid, 256, 0, stream>>>(P, Cp, Lp);
    scan_phase_b<<<CHN / 256, 256, 0, stream>>>(Cp, Lp, carry);
    scan_phase_c<<<sgrid, 256, 0, stream>>>(P, carry, ids);
}

// Round 6
// 253.426 us; speedup vs baseline: 1.2347x; 1.2347x over previous
//
#include <hip/hip_runtime.h>
#include <hip/hip_fp16.h>
#include <math.h>

#define S_LEN 8192
#define D_DIM 1024
#define B_DIM 4
#define M_DIM (B_DIM * S_LEN)          // 32768
#define BSD   ((size_t)M_DIM * D_DIM)
#define CHN   (B_DIM * D_DIM)          // 4096 channels
#define CHUNK 64
#define NCH   (S_LEN / CHUNK)          // 128

typedef _Float16 f16x8 __attribute__((ext_vector_type(8)));
typedef __attribute__((ext_vector_type(4))) float f32x4;
typedef unsigned int u32;

__device__ __forceinline__ u32 pk2h(float a, float b) {
    auto h = __builtin_amdgcn_cvt_pkrtz(a, b);
    u32 r; __builtin_memcpy(&r, &h, 4); return r;
}

__device__ __forceinline__ void gload16(const void* g, void* l) {
    __builtin_amdgcn_global_load_lds(
        (const __attribute__((address_space(1))) u32*)g,
        (__attribute__((address_space(3))) u32*)l,
        16, 0, 0);
}

// ---------------------------------------------------------------------------
// Kernel 0: W [1024][2048] fp32 -> Wt [2048][1024] fp16 (transposed), once.
// ---------------------------------------------------------------------------
__global__ __launch_bounds__(256) void w_to_f16t(
    const float* __restrict__ W, unsigned short* __restrict__ Wt)
{
    __shared__ float T[64][65];
    const int t  = threadIdx.x;
    const int n0 = (int)blockIdx.x * 64;
    const int k0 = (int)blockIdx.y * 64;
    #pragma unroll
    for (int p = 0; p < 4; ++p) {
        int u = p * 256 + t;
        int r = u >> 4, c4 = (u & 15) * 4;
        float4 v = *(const float4*)&W[(size_t)(k0 + r) * 2048 + n0 + c4];
        T[r][c4 + 0] = v.x; T[r][c4 + 1] = v.y;
        T[r][c4 + 2] = v.z; T[r][c4 + 3] = v.w;
    }
    __syncthreads();
    #pragma unroll
    for (int p = 0; p < 2; ++p) {
        int u = p * 256 + t;
        int n = u >> 3, kc = (u & 7) * 8;
        u32 out[4];
        #pragma unroll
        for (int j = 0; j < 4; ++j)
            out[j] = pk2h(T[kc + 2 * j][n], T[kc + 2 * j + 1][n]);
        *(uint4*)&Wt[(size_t)(n0 + n) * 1024 + k0 + kc] = *(uint4*)out;
    }
}

// ---------------------------------------------------------------------------
// Kernel 0b: x fp32 -> xh fp16, XOR-pre-swizzled (rule 21 source-side).
// ---------------------------------------------------------------------------
__global__ __launch_bounds__(256) void x_to_f16sw(
    const float* __restrict__ x, unsigned short* __restrict__ xh)
{
    int tid = (int)blockIdx.x * 256 + threadIdx.x;
    int m  = tid >> 7;
    int cg = tid & 127;
    const float4* src = (const float4*)&x[(size_t)m * 1024 + cg * 8];
    float4 v0 = src[0], v1 = src[1];
    u32 o[4] = { pk2h(v0.x, v0.y), pk2h(v0.z, v0.w),
                 pk2h(v1.x, v1.y), pk2h(v1.z, v1.w) };
    int j   = cg & 7;
    int cgd = (cg & ~7) | (j ^ (m & 7));
    *(uint4*)&xh[(size_t)m * 1024 + cgd * 8] = *(uint4*)o;
}

// ---------------------------------------------------------------------------
// Kernel 1 (main): r19 K-loop (best measured, 165 us) + r22 fused epilogue.
// r22: scan_a's 128 MB re-read of P is eliminated by computing the per-64-
// chunk affine (C = prod c, L = inclusive scan result from h=0) inside the
// GEMM epilogue. h -> c*h+v maps compose associatively:
//   quad (4 rows, in-lane, r ascending) -> LDS stash (Ah reused, 64 KB) ->
//   512 threads compose 16 quads in row order -> Cp/Lp write.
// Row order check: row = m0 + wm*128 + mf*16 + lg*4 + r; quad idx
// rq = wm*32 + mf*4 + lg is ascending in row; chunk (64 rows) = 16 quads.
// K-loop, mapping, swizzle untouched from r19.
// ---------------------------------------------------------------------------
__global__ __launch_bounds__(512, 2) void gemm_8p(
    const unsigned short* __restrict__ xh, const unsigned short* __restrict__ Wt,
    const int* __restrict__ ids, u32* __restrict__ P,
    float* __restrict__ Cp, float* __restrict__ Lp)
{
    __shared__ __align__(16) unsigned short Ah[2 * 256 * 64]; // 2 x 32 KB
    __shared__ __align__(16) unsigned short Bt[2 * 256 * 64]; // 2 x 32 KB

    const int t    = threadIdx.x;
    const int lane = t & 63;
    const int wid  = t >> 6;        // 0..7
    const int wm   = wid >> 2;      // 0..1 : 128-row half
    const int wd   = wid & 3;       // 0..3 : 32-dcol group

    const int lin  = (int)blockIdx.x;   // 1024 blocks
    const int xcd  = lin & 7;
    const int slot = lin >> 3;
    const int m0   = (xcd * 16 + (slot >> 3)) * 256;
    const int c0   = (slot & 7) * 128;

    f32x4 accH[8][2], accG[8][2];
    #pragma unroll
    for (int i = 0; i < 8; ++i)
        #pragma unroll
        for (int j = 0; j < 2; ++j) {
            accH[i][j] = (f32x4)0.0f;
            accG[i][j] = (f32x4)0.0f;
        }

    // stage one half-tile (2 gload16/thread)
    auto stageA = [&](int kb, int buf, int half) {
        char* Ad = (char*)Ah + (buf << 15) + (half << 14);
        #pragma unroll
        for (int i = 0; i < 2; ++i) {
            int sl  = i * 512 + t;            // 0..1023
            int row = half * 128 + (sl >> 3);
            int c   = sl & 7;                 // physical chunk (pre-swizzled)
            const unsigned short* src =
                xh + ((size_t)(m0 + row) << 10) + kb + (c << 3);
            gload16(src, Ad + (size_t)sl * 16);
        }
    };
    auto stageB = [&](int kb, int buf, int half) {
        char* Bd = (char*)Bt + (buf << 15) + (half << 14);
        #pragma unroll
        for (int i = 0; i < 2; ++i) {
            int sl  = i * 512 + t;
            int col = sl >> 3;                // 0..127
            int kc  = (sl & 7) ^ (col & 7);
            const unsigned short* src =
                Wt + ((size_t)(half * 1024 + c0 + col) << 10) + kb + (kc << 3);
            gload16(src, Bd + (size_t)sl * 16);
        }
    };

    // fragment reads
    auto readA = [&](const char* Ab, int kk, f16x8 a[8]) {
        int chunk = kk * 4 + (lane >> 4);
        #pragma unroll
        for (int mf = 0; mf < 8; ++mf) {
            int row = wm * 128 + mf * 16 + (lane & 15);
            a[mf] = *(const f16x8*)(Ab + row * 128 + ((chunk ^ (row & 7)) << 4));
        }
    };
    auto readB = [&](const char* Bb, int kk, int hg, f16x8 b[2]) {
        int chunk = kk * 4 + (lane >> 4);
        #pragma unroll
        for (int df = 0; df < 2; ++df) {
            int col = wd * 32 + df * 16 + (lane & 15);
            b[df] = *(const f16x8*)(Bb + (hg * 128 + col) * 128
                                       + ((chunk ^ (col & 7)) << 4));
        }
    };

    #define MMA_CLUSTER(ACC, AV, BV)                                       \
        __builtin_amdgcn_s_setprio(1);                                     \
        _Pragma("unroll")                                                  \
        for (int mf = 0; mf < 8; ++mf)                                     \
            _Pragma("unroll")                                              \
            for (int df = 0; df < 2; ++df)                                 \
                ACC[mf][df] = __builtin_amdgcn_mfma_f32_16x16x32_f16(      \
                    AV[mf], BV[df], ACC[mf][df], 0, 0, 0);                 \
        __builtin_amdgcn_s_setprio(0);

    // ---- prologue: stage tile 0 fully (A0,A1,B0,B1 = 8 loads) ----
    stageA(0, 0, 0); stageA(0, 0, 1); stageB(0, 0, 0); stageB(0, 0, 1);
    asm volatile("s_waitcnt vmcnt(0)" ::: "memory");
    __builtin_amdgcn_sched_barrier(0);
    __builtin_amdgcn_s_barrier();

    for (int tt = 0; tt < 16; ++tt) {
        const int buf   = tt & 1;
        const int kbn   = (tt + 1) << 6;
        const bool more = tt < 15;
        const char* Ab = (const char*)Ah + (buf << 15);
        const char* Bb = (const char*)Bt + (buf << 15);
        f16x8 a0[8], a1[8], bh0[2], bg0[2], bh1[2], bg1[2];

        // ---- R0: reads (kk0,H); stage A'; pre-read (kk0,G); MFMA H0 ----
        readA(Ab, 0, a0); readB(Bb, 0, 0, bh0);
        if (more) { stageA(kbn, buf ^ 1, 0); stageA(kbn, buf ^ 1, 1); }
        asm volatile("s_waitcnt lgkmcnt(0)" ::: "memory");
        __builtin_amdgcn_sched_barrier(0);
        readB(Bb, 0, 1, bg0);                 // drains under MFMA H0
        __builtin_amdgcn_sched_barrier(0);
        MMA_CLUSTER(accH, a0, bh0)

        // ---- P1: MFMA G0; pre-read (kk1,H); stage B' ----
        asm volatile("s_waitcnt lgkmcnt(0)" ::: "memory");
        __builtin_amdgcn_sched_barrier(0);
        readA(Ab, 1, a1); readB(Bb, 1, 0, bh1);   // drain under MFMA G0
        if (more) { stageB(kbn, buf ^ 1, 0); stageB(kbn, buf ^ 1, 1); }
        __builtin_amdgcn_sched_barrier(0);
        MMA_CLUSTER(accG, a0, bg0)

        // ---- P2: MFMA H1; pre-read (kk1,G) ----
        asm volatile("s_waitcnt lgkmcnt(0)" ::: "memory");
        __builtin_amdgcn_sched_barrier(0);
        readB(Bb, 1, 1, bg1);                 // drains under MFMA H1
        __builtin_amdgcn_sched_barrier(0);
        MMA_CLUSTER(accH, a1, bh1)

        // ---- P3: MFMA G1; retire staging; buf-swap barrier ----
        asm volatile("s_waitcnt lgkmcnt(0)" ::: "memory");
        __builtin_amdgcn_sched_barrier(0);
        MMA_CLUSTER(accG, a1, bg1)
        if (more) {
            // 8 staging loads issued 2-3 phases ago -> drain ~free
            asm volatile("s_waitcnt vmcnt(0)" ::: "memory");
            __builtin_amdgcn_sched_barrier(0);
            __builtin_amdgcn_s_barrier();     // publishes buf^1, protects buf
        }
    }
    #undef MMA_CLUSTER

    // ---- epilogue: P-write + fused per-64-chunk affine (scan_a fusion) ----
    // All waves must be done reading the last tile before Ah is reused.
    __builtin_amdgcn_s_barrier();
    float* Caff = (float*)Ah;   // [64 rq][128 col][2] = 64 KB (Ah reused)

    #pragma unroll
    for (int mf = 0; mf < 8; ++mf) {
        int mbase = m0 + wm * 128 + mf * 16 + (lane >> 4) * 4;
        float Cr[2] = {1.0f, 1.0f};
        float Lr[2] = {0.0f, 0.0f};
        #pragma unroll
        for (int r = 0; r < 4; ++r) {
            int m = mbase + r;
            int b = m >> 13;
            int s = m & 8191;
            bool reset = (s > 0) && (ids[b * S_LEN + s - 1] == 0);
            #pragma unroll
            for (int df = 0; df < 2; ++df) {
                int d = c0 + wd * 32 + df * 16 + (lane & 15);
                float hid = accH[mf][df][r];
                float g   = accG[mf][df][r];
                float eg  = __expf(-g);
                float z   = 1.0f / (1.0f + eg);
                float c   = eg * z;
                float gt  = (hid >= 0.0f) ? (hid + 0.5f)
                                          : 1.0f / (1.0f + __expf(-hid));
                float v   = z * gt;
                if (reset) { c = 0.0f; v = 0.0f; }
                __half2 h2 = __floats2half2_rn(c, v);
                u32 packed;
                __builtin_memcpy(&packed, &h2, 4);
                P[(size_t)m * D_DIM + d] = packed;
                // quad affine, r ascending: h' = c*h + v
                Lr[df] = fmaf(c, Lr[df], v);
                Cr[df] *= c;
            }
        }
        int rq = wm * 32 + mf * 4 + (lane >> 4);
        #pragma unroll
        for (int df = 0; df < 2; ++df) {
            int col = wd * 32 + df * 16 + (lane & 15);
            Caff[(rq * 128 + col) * 2 + 0] = Cr[df];
            Caff[(rq * 128 + col) * 2 + 1] = Lr[df];
        }
    }
    __builtin_amdgcn_s_barrier();
    {
        // 512 threads, 512 tasks: (sub-chunk sc 0..3) x (col 0..127)
        int sc  = t >> 7;
        int col = t & 127;
        float C = 1.0f, L = 0.0f;
        #pragma unroll
        for (int q = 0; q < 16; ++q) {
            int rq = sc * 16 + q;
            float cq = Caff[(rq * 128 + col) * 2 + 0];
            float lq = Caff[(rq * 128 + col) * 2 + 1];
            L = fmaf(cq, L, lq);
            C *= cq;
        }
        int m    = m0 + sc * 64;
        int b    = m >> 13;
        int cidx = (m & 8191) >> 6;
        int ch   = (b << 10) | (c0 + col);
        Cp[cidx * CHN + ch] = C;
        Lp[cidx * CHN + ch] = L;
    }
}

// ---------------------------------------------------------------------------
// Kernel 1 (fallback, ws too small): r10 kernel verbatim.
// ---------------------------------------------------------------------------
__global__ __launch_bounds__(256, 3) void gemm_fb(
    const float* __restrict__ x, const unsigned short* __restrict__ Wt,
    const int* __restrict__ ids, u32* __restrict__ P)
{
    __shared__ __align__(16) unsigned short Ah[128 * 64];
    __shared__ __align__(16) unsigned short Bt[2 * 64 * 64];

    const int t    = threadIdx.x;
    const int lane = t & 63;
    const int wid  = t >> 6;
    const int wm   = wid >> 1;
    const int wd   = wid & 1;

    const int lin  = (int)blockIdx.y * (int)gridDim.x + (int)blockIdx.x;
    const int xcd  = lin & 7;
    const int slot = lin >> 3;
    const int m0   = (xcd * 32 + (slot >> 4)) * 128;
    const int c0   = (slot & 15) * 64;

    f32x4 accH[4][2], accG[4][2];
    #pragma unroll
    for (int i = 0; i < 4; ++i)
        #pragma unroll
        for (int j = 0; j < 2; ++j) {
            accH[i][j] = (f32x4)0.0f;
            accG[i][j] = (f32x4)0.0f;
        }

    for (int kb = 0; kb < 1024; kb += 64) {
        __syncthreads();
        #pragma unroll
        for (int i = 0; i < 4; ++i) {
            int slotb = wid * 256 + i * 64;
            int sl  = slotb + lane;
            int hg  = sl >> 9;
            int col = (sl >> 3) & 63;
            int kc  = (sl & 7) ^ (col & 7);
            const unsigned short* src =
                Wt + ((size_t)(hg * 1024 + c0 + col) << 10) + kb + (kc << 3);
            gload16(src, (char*)Bt + (size_t)slotb * 16);
        }
        #pragma unroll
        for (int p = 0; p < 8; ++p) {
            int s   = p * 256 + t;
            int row = s >> 4;
            int c4  = s & 15;
            float4 v = *(const float4*)&x[(size_t)(m0 + row) * 1024 + kb + c4 * 4];
            uint2 h;
            h.x = pk2h(v.x, v.y);
            h.y = pk2h(v.z, v.w);
            int byte = row * 128 + ((((c4 >> 1) ^ (row & 7))) << 4) + ((c4 & 1) << 3);
            *(uint2*)((char*)Ah + byte) = h;
        }
        __syncthreads();
        #pragma unroll
        for (int kk = 0; kk < 2; ++kk) {
            f16x8 bh[2], bg[2];
            #pragma unroll
            for (int df = 0; df < 2; ++df) {
                int col = wd * 32 + df * 16 + (lane & 15);
                int chunk = kk * 4 + (lane >> 4);
                int byte = col * 128 + ((chunk ^ (col & 7)) << 4);
                bh[df] = *(const f16x8*)((const char*)Bt + byte);
                bg[df] = *(const f16x8*)((const char*)Bt + 8192 + byte);
            }
            #pragma unroll
            for (int mf = 0; mf < 4; ++mf) {
                int row = wm * 64 + mf * 16 + (lane & 15);
                int chunk = kk * 4 + (lane >> 4);
                int byte = row * 128 + ((chunk ^ (row & 7)) << 4);
                f16x8 a = *(const f16x8*)((const char*)Ah + byte);
                #pragma unroll
                for (int df = 0; df < 2; ++df) {
                    accH[mf][df] = __builtin_amdgcn_mfma_f32_16x16x32_f16(
                        a, bh[df], accH[mf][df], 0, 0, 0);
                    accG[mf][df] = __builtin_amdgcn_mfma_f32_16x16x32_f16(
                        a, bg[df], accG[mf][df], 0, 0, 0);
                }
            }
        }
    }

    #pragma unroll
    for (int mf = 0; mf < 4; ++mf) {
        int mbase = m0 + wm * 64 + mf * 16 + (lane >> 4) * 4;
        #pragma unroll
        for (int r = 0; r < 4; ++r) {
            int m = mbase + r;
            int b = m >> 13;
            int s = m & 8191;
            bool reset = (s > 0) && (ids[b * S_LEN + s - 1] == 0);
            #pragma unroll
            for (int df = 0; df < 2; ++df) {
                int d = c0 + wd * 32 + df * 16 + (lane & 15);
                float hid = accH[mf][df][r];
                float g   = accG[mf][df][r];
                float eg  = __expf(-g);
                float z   = 1.0f / (1.0f + eg);
                float c   = eg * z;
                float gt  = (hid >= 0.0f) ? (hid + 0.5f)
                                          : 1.0f / (1.0f + __expf(-hid));
                float v   = z * gt;
                if (reset) { c = 0.0f; v = 0.0f; }
                __half2 h2 = __floats2half2_rn(c, v);
                u32 packed;
                __builtin_memcpy(&packed, &h2, 4);
                P[(size_t)m * D_DIM + d] = packed;
            }
        }
    }
}

// ---------------------------------------------------------------------------
// Scan phases, linear space: h_s = c_s * h_{s-1} + v_s. Pure FMA.
// scan_phase_a only used on the fallback path (main path fuses it into gemm).
// ---------------------------------------------------------------------------
__global__ __launch_bounds__(256) void scan_phase_a(
    const u32* __restrict__ P,
    float* __restrict__ Cp, float* __restrict__ Lp)
{
    int ch0 = (blockIdx.x * 256 + threadIdx.x) * 4;
    int c   = blockIdx.y;
    int b   = ch0 >> 10;
    int d0  = ch0 & 1023;
    size_t base = (size_t)b * S_LEN * D_DIM + d0;
    int s0 = c * CHUNK;

    float C[4] = {1.f, 1.f, 1.f, 1.f};
    float H[4] = {0.f, 0.f, 0.f, 0.f};
    for (int s = 0; s < CHUNK; ++s) {
        uint4 q = *(const uint4*)&P[base + (size_t)(s0 + s) * D_DIM];
        u32 qs[4] = {q.x, q.y, q.z, q.w};
        #pragma unroll
        for (int j = 0; j < 4; ++j) {
            __half2 h2;
            __builtin_memcpy(&h2, &qs[j], 4);
            float cc = __low2float(h2);
            float vv = __high2float(h2);
            H[j] = fmaf(cc, H[j], vv);
            C[j] *= cc;
        }
    }
    *(float4*)&Cp[c * CHN + ch0] = *(float4*)C;
    *(float4*)&Lp[c * CHN + ch0] = *(float4*)H;
}

__global__ __launch_bounds__(256) void scan_phase_b(
    const float* __restrict__ Cp, const float* __restrict__ Lp,
    float* __restrict__ carry)
{
    int ch = blockIdx.x * 256 + threadIdx.x;
    float h = 0.0f;
    for (int c = 0; c < NCH; ++c) {
        carry[c * CHN + ch] = h;
        h = fmaf(Cp[c * CHN + ch], h, Lp[c * CHN + ch]);
    }
}

__global__ __launch_bounds__(256) void scan_phase_c(
    u32* __restrict__ Pio,
    const float* __restrict__ carry,
    const int* __restrict__ ids)
{
    int ch0 = (blockIdx.x * 256 + threadIdx.x) * 4;
    int c   = blockIdx.y;
    int b   = ch0 >> 10;
    int d0  = ch0 & 1023;
    size_t base = (size_t)b * S_LEN * D_DIM + d0;
    int s0 = c * CHUNK;

    float H[4];
    *(float4*)H = *(const float4*)&carry[c * CHN + ch0];

    for (int s = 0; s < CHUNK; ++s) {
        size_t idx = base + (size_t)(s0 + s) * D_DIM;
        uint4 q = *(const uint4*)&Pio[idx];
        u32 qs[4] = {q.x, q.y, q.z, q.w};
        u32 os[4];
        #pragma unroll
        for (int j = 0; j < 4; ++j) {
            __half2 h2;
            __builtin_memcpy(&h2, &qs[j], 4);
            float cc = __low2float(h2);
            float vv = __high2float(h2);
            H[j] = fmaf(cc, H[j], vv);
            os[j] = __float_as_uint(H[j]);
        }
        *(uint4*)&Pio[idx] = *(uint4*)os;
    }
    if (c == NCH - 1) {
        bool pad = (ids[b * S_LEN + (S_LEN - 1)] == 0);
        u32 os[4];
        #pragma unroll
        for (int j = 0; j < 4; ++j)
            os[j] = __float_as_uint(pad ? 0.0f : H[j]);
        *(uint4*)&Pio[BSD + (size_t)b * D_DIM + d0] = *(uint4*)os;
    }
}

extern "C" void kernel_launch(void* const* d_in, const int* in_sizes, int n_in,
                              void* d_out, int out_size, void* d_ws, size_t ws_size,
                              hipStream_t stream) {
    const float* x   = (const float*)d_in[0];
    const float* W   = (const float*)d_in[1];
    const int*   ids = (const int*)d_in[2];

    u32* P = (u32*)d_out;
    unsigned short* Wt = (unsigned short*)d_ws;                   // 4 MB @ 0
    float* Cp    = (float*)((char*)d_ws + (size_t) 4 * 1024 * 1024);
    float* Lp    = (float*)((char*)d_ws + (size_t) 6 * 1024 * 1024);
    float* carry = (float*)((char*)d_ws + (size_t) 8 * 1024 * 1024);
    unsigned short* xh = (unsigned short*)((char*)d_ws + (size_t)10 * 1024 * 1024);
    const size_t need = (size_t)10 * 1024 * 1024 + BSD * 2;       // 74 MB

    w_to_f16t<<<dim3(32, 16), 256, 0, stream>>>(W, Wt);

    dim3 sgrid(CHN / 1024, NCH);
    if (ws_size >= need) {
        x_to_f16sw<<<(M_DIM * 128) / 256, 256, 0, stream>>>(x, xh);
        gemm_8p<<<1024, 512, 0, stream>>>(xh, Wt, ids, P, Cp, Lp);
        // scan_phase_a fused into gemm_8p epilogue
    } else {
        dim3 ggrid(D_DIM / 64, M_DIM / 128);
        gemm_fb<<<ggrid, 256, 0, stream>>>(x, Wt, ids, P);
        scan_phase_a<<<sgrid, 256, 0, stream>>>(P, Cp, Lp);
    }

    scan_phase_b<<<CHN / 256, 256, 0, stream>>>(Cp, Lp, carry);
    scan_phase_c<<<sgrid, 256, 0, stream>>>(P, carry, ids);
}